// Round 14
// baseline (185.100 us; speedup 1.0000x reference)
//
#include <hip/hip_runtime.h>
#include <hip/hip_cooperative_groups.h>
#include <math.h>

namespace cg = cooperative_groups;

#define CC 64
#define HWN 4096
#define QB 64            // q per block; ALL 8 waves compute the same 64 q
#define KSPLIT 8         // each wave privately owns 512 k
#define KT 32
#define NITER (HWN / KSPLIT / KT)   // 16 chunks per wave
#define NKC (HWN / KT)              // 128 k-chunks per batch

typedef __attribute__((ext_vector_type(8))) short bf16x8;
typedef __attribute__((ext_vector_type(4))) float f32x4;

// precomputed bf16 operand layouts (written by phase 1 every launch)
__device__ __align__(16) unsigned short g_bgT[4][HWN][CC];       // (bg*sb)^T [b][k][c]
__device__ __align__(16) unsigned short g_bgN[4][NKC][CC][KT];   // bf16(bg) chunk-major
__device__ __align__(16) unsigned short g_fgT[4][HWN][CC];       // (fg*sf)^T [b][q][c]

static __device__ __forceinline__ unsigned int f2bf(float x) {   // RNE
  union { float f; unsigned int u; } v; v.f = x;
  return (v.u + 0x7fffu + ((v.u >> 16) & 1u)) >> 16;
}
static __device__ __forceinline__ unsigned int packbf(float lo, float hi) {
  return f2bf(lo) | (f2bf(hi) << 16);
}

// ---- fused: prep phase + grid sync + attn phase (one launch, one boundary) ----
// Phase 1 = r13 prep: 1024 tiles (which2 x b4 x kc128), 4 per block as two
//   256-thread halves x 2 rounds. LDS [0,16640) aliases the staging region.
// __threadfence() = device-scope release (L2 writeback) so cross-XCD reads after
//   grid.sync() can't see stale/dirty data; readers' L2s hold no g_* lines this
//   kernel (phase 1 only writes them), so no reader-side invalidation needed.
// Phase 2 = r13 attn byte-identical (best measured config).
// LDS: [0,65536)        bgT staging, wave w: [w*8192 + buf*4096), swizzled
//      [65536,106496)   P per wave [64q][40k] ushort (5120 B each)
//      [106496,108544)  mL [8ks][64q] f32
//      epilogue aliases [0,69632) as mO [8ks][64c][34] f32 (two q-half passes)
#define P_OFF 65536
#define ML_OFF 106496
#define SMEM_BYTES 108544
__global__ __launch_bounds__(512, 2) void fused_kernel(const float* __restrict__ bg,
                                                       const float* __restrict__ fgin,
                                                       const float* __restrict__ mask,
                                                       float* __restrict__ out) {
  __shared__ __align__(16) char smem[SMEM_BYTES];
  const int tid = threadIdx.x;
  const int wg = blockIdx.x;

  // ================= phase 1: prep =================
  {
    float* plds = (float*)smem + (tid >> 8) * (32 * 65);   // per-half tile buffer
    const int t256 = tid & 255;
#pragma unroll
    for (int round = 0; round < 2; ++round) {
      const int tile = wg * 4 + round * 2 + (tid >> 8);    // 0..1023
      const int kc = tile & 127, bb = (tile >> 7) & 3, which = tile >> 9;
      const float* src = (which ? fgin : bg) + (size_t)bb * CC * HWN + kc * KT;

      // stage 32k x 64c tile transposed: thread (c, k-range) loads 2 float4
      {
        int c = t256 >> 2, k0 = (t256 & 3) * 8;
#pragma unroll
        for (int j4 = 0; j4 < 2; ++j4) {
          float4 v = *(const float4*)(src + (size_t)c * HWN + k0 + 4 * j4);
          plds[(k0 + 4 * j4 + 0) * 65 + c] = v.x;
          plds[(k0 + 4 * j4 + 1) * 65 + c] = v.y;
          plds[(k0 + 4 * j4 + 2) * 65 + c] = v.z;
          plds[(k0 + 4 * j4 + 3) * 65 + c] = v.w;
        }
      }
      __syncthreads();

      const int k = t256 >> 3, u = t256 & 7;
      // column norm: 8 threads per k, each sums 8 c, combine via shfl (in-wave)
      float ss = 0.f;
#pragma unroll
      for (int j = 0; j < 8; ++j) {
        float v = plds[k * 65 + u * 8 + j];
        ss = fmaf(v, v, ss);
      }
      ss += __shfl_xor(ss, 1, 64);
      ss += __shfl_xor(ss, 2, 64);
      ss += __shfl_xor(ss, 4, 64);
      const float s = 1.0f / fmaxf(sqrtf(ss), 1e-12f);

      // write scaled transposed [b][k][c] bf16: 8 threads/k, one uint4 each
      {
        unsigned int* gT32 = (unsigned int*)(which ? &g_fgT[0][0][0] : &g_bgT[0][0][0]);
        size_t R = (size_t)bb * HWN + kc * KT + k;
        unsigned int w4[4];
#pragma unroll
        for (int i = 0; i < 4; ++i) {
          int c2 = u * 8 + 2 * i;
          w4[i] = packbf(plds[k * 65 + c2] * s, plds[k * 65 + c2 + 1] * s);
        }
        *(uint4*)&gT32[R * 32 + u * 4] = make_uint4(w4[0], w4[1], w4[2], w4[3]);
      }

      // bg tiles also write raw cast, chunk-major [b][kc][c][32]
      if (which == 0) {
        unsigned int* gN32 = (unsigned int*)&g_bgN[0][0][0][0];
        int cN = t256 >> 2, vN = t256 & 3;
        unsigned int n4[4];
#pragma unroll
        for (int i = 0; i < 4; ++i) {
          int kk = vN * 8 + 2 * i;
          n4[i] = packbf(plds[kk * 65 + cN], plds[(kk + 1) * 65 + cN]);
        }
        size_t RN = (((size_t)bb * NKC + kc) * CC + cN) * (KT / 2) + vN * 4;
        *(uint4*)&gN32[RN] = make_uint4(n4[0], n4[1], n4[2], n4[3]);
      }
      __syncthreads();   // LDS reuse across rounds
    }
  }

  __threadfence();               // release: L2 writeback before cross-XCD reads
  cg::this_grid().sync();        // all prep visible; also a block barrier

  // ================= phase 2: attn (r13 body) =================
  // bijective XCD swizzle (256 % 8 == 0): 2 XCDs per batch -> 2MB working set/L2
  const int wgp = (wg & 7) * 32 + (wg >> 3);
  const int b = wgp >> 6;
  const int q0 = (wgp & 63) * QB;
  const int lane = tid & 63;
  const int ks = tid >> 6;    // 0..7, private K-split (512 k each)
  const int m16 = lane & 15;
  const int quad = lane >> 4;

  // fg B-fragments (64 q), loaded once from global (L2/L3)
  bf16x8 Bf[4][2];
#pragma unroll
  for (int qf = 0; qf < 4; ++qf)
#pragma unroll
    for (int h = 0; h < 2; ++h)
      Bf[qf][h] = *(const bf16x8*)&g_fgT[b][q0 + qf * 16 + m16][h * 32 + quad * 8];

  // bgT lane-swizzled staging sources (swizzle on global side; LDS lane-ordered)
  const unsigned short* srcT[4];
#pragma unroll
  for (int t = 0; t < 4; ++t) {
    int uT = t * 64 + lane;
    int kk = uT >> 3, pos = uT & 7, j = pos ^ (kk & 7);
    srcT[t] = &g_bgT[b][ks * 512 + kk][j * 8];
  }

  // bgN per-lane base (chunk-major): chunk block ks*16, row c=m16, k-slice quad*8
  const unsigned short* pN = &g_bgN[b][ks * 16][m16][quad * 8];

  unsigned short* P = (unsigned short*)(smem + P_OFF + ks * 5120);  // [64 q][40 k]
  float* mL = (float*)(smem + ML_OFF);

  float l_run[4] = {0.f, 0.f, 0.f, 0.f};   // per-lane partial sums per q-frag
  f32x4 O[4][4];                            // [c-tile][q-frag]
#pragma unroll
  for (int t = 0; t < 4; ++t)
#pragma unroll
    for (int qf = 0; qf < 4; ++qf) O[t][qf] = (f32x4){0.f, 0.f, 0.f, 0.f};

  char* const myT = smem + ks * 8192;       // this wave's bgT staging (2 x 4KB)

  auto stageT = [&](int bufsel) {
#pragma unroll
    for (int t = 0; t < 4; ++t) {
      __builtin_amdgcn_global_load_lds(
          (const __attribute__((address_space(1))) unsigned int*)srcT[t],
          (__attribute__((address_space(3))) unsigned int*)(myT + bufsel * 4096 + t * 1024),
          16, 0, 0);
      srcT[t] += KT * CC;   // next chunk
    }
  };

  bf16x8 A0r[4], A1r[4];   // bgN register double-buffer (static-indexed)
  auto loadN = [&](bf16x8 (&A)[4], int ch) {
#pragma unroll
    for (int t = 0; t < 4; ++t)
      A[t] = *(const bf16x8*)(pN + (size_t)ch * (CC * KT) + t * 16 * KT);
  };

  // one pipeline step: compute chunk `it` from LDS buf `co` + regs Ac,
  // prefetching chunk it+1 into buf `co^1` + regs An.
  auto iter = [&](int it, int co, bf16x8 (&Ac)[4], bf16x8 (&An)[4]) {
    if (it + 1 < NITER) {
      stageT(co ^ 1);        // 4 x global_load_lds (bgT, chunk it+1)
      loadN(An, it + 1);     // 4 x global_load_dwordx4 (bgN, chunk it+1)
      // oldest-8 wait: chunk-it bgT glds AND chunk-it bgN reg loads complete
      asm volatile("s_waitcnt vmcnt(8)" ::: "memory");
    } else {
      asm volatile("s_waitcnt vmcnt(0)" ::: "memory");
    }

    const char* baseT = myT + co * 4096;

    // scores S[32k][64q] = (bg*sb)^T · (fg*sf): 4 ds_read feed 16 MFMA
    f32x4 S[4][2];
    __builtin_amdgcn_s_setprio(1);
#pragma unroll
    for (int i = 0; i < 2; ++i) {
      int kk = 16 * i + m16;
      bf16x8 T0 = *(const bf16x8*)(baseT + kk * 128 + ((quad) ^ (kk & 7)) * 16);
      bf16x8 T1 = *(const bf16x8*)(baseT + kk * 128 + ((4 + quad) ^ (kk & 7)) * 16);
#pragma unroll
      for (int qf = 0; qf < 4; ++qf) {
        f32x4 acc = {0.f, 0.f, 0.f, 0.f};
        acc = __builtin_amdgcn_mfma_f32_16x16x32_bf16(T0, Bf[qf][0], acc, 0, 0, 0);
        acc = __builtin_amdgcn_mfma_f32_16x16x32_bf16(T1, Bf[qf][1], acc, 0, 0, 0);
        S[qf][i] = acc;
      }
    }
    __builtin_amdgcn_s_setprio(0);

    // fixed-max softmax: cosines, |s| <= 1 -> p = exp(s-1); per-lane deferred sum
#pragma unroll
    for (int qf = 0; qf < 4; ++qf)
#pragma unroll
      for (int i = 0; i < 2; ++i) {
        float pe[4];
#pragma unroll
        for (int r = 0; r < 4; ++r) {
          pe[r] = __expf(S[qf][i][r] - 1.0f);
          l_run[qf] += pe[r];
        }
        // pack P -> per-wave LDS [q][k] bf16 (round-half-up via +0x8000, v_perm)
        union { float f; unsigned int u; } x0, x1, x2, x3;
        x0.f = pe[0]; x1.f = pe[1]; x2.f = pe[2]; x3.f = pe[3];
        unsigned int p01 = __builtin_amdgcn_perm(x1.u + 0x8000u, x0.u + 0x8000u, 0x07060302u);
        unsigned int p23 = __builtin_amdgcn_perm(x3.u + 0x8000u, x2.u + 0x8000u, 0x07060302u);
        *(uint2*)&P[(qf * 16 + m16) * 40 + 16 * i + quad * 4] = make_uint2(p01, p23);
      }

    // PV: O[c][q] += bg[c][k] · P[k][q]   (per-wave P + private regs: no barrier)
    bf16x8 Pf[4];
#pragma unroll
    for (int qf = 0; qf < 4; ++qf)
      Pf[qf] = *(const bf16x8*)&P[(qf * 16 + m16) * 40 + quad * 8];
    __builtin_amdgcn_s_setprio(1);
#pragma unroll
    for (int t = 0; t < 4; ++t)
#pragma unroll
      for (int qf = 0; qf < 4; ++qf)
        O[t][qf] = __builtin_amdgcn_mfma_f32_16x16x32_bf16(Ac[t], Pf[qf], O[t][qf], 0, 0, 0);
    __builtin_amdgcn_s_setprio(0);
  };

  // prologue: chunk 0 in flight (4 glds + 4 reg loads)
  stageT(0);
  loadN(A0r, 0);

  for (int it2 = 0; it2 < NITER; it2 += 2) {
    iter(it2,     0, A0r, A1r);
    iter(it2 + 1, 1, A1r, A0r);
  }

  // ---- merge 8 K-splits + epilogue (two q-half passes; mO aliases staging+P) ----
#pragma unroll
  for (int qf = 0; qf < 4; ++qf) {
    l_run[qf] += __shfl_xor(l_run[qf], 16, 64);
    l_run[qf] += __shfl_xor(l_run[qf], 32, 64);
  }
  if (quad == 0) {
#pragma unroll
    for (int qf = 0; qf < 4; ++qf) mL[ks * 64 + qf * 16 + m16] = l_run[qf];
  }
  float* mO = (float*)smem;   // [8 ks][64 c][34]
  const float* fgB = fgin + (size_t)b * CC * HWN;
  const float* mk = mask + (size_t)b * HWN;
  float* outB = out + (size_t)b * CC * HWN;

#pragma unroll
  for (int half = 0; half < 2; ++half) {
    __syncthreads();   // pass 0: all waves done with staging/P reads; pass 1: reduce done
#pragma unroll
    for (int qh = 0; qh < 2; ++qh) {
      int qf = half * 2 + qh;
#pragma unroll
      for (int t = 0; t < 4; ++t)
#pragma unroll
        for (int r = 0; r < 4; ++r)
          mO[(ks * 64 + 16 * t + quad * 4 + r) * 34 + qh * 16 + m16] = O[t][qf][r];
    }
    __syncthreads();
    {
      int q = tid & 31, cb = tid >> 5;   // cb 0..15
      int qglob = q0 + half * 32 + q;
      float L = 0.f;
#pragma unroll
      for (int s = 0; s < 8; ++s) L += mL[s * 64 + half * 32 + q];
      float invL = 1.0f / L;
      float mv = mk[qglob];
#pragma unroll
      for (int e = 0; e < 4; ++e) {
        int c = cb * 4 + e;
        float acc = 0.f;
#pragma unroll
        for (int s = 0; s < 8; ++s) acc += mO[(s * 64 + c) * 34 + q];
        float att = acc * invL;
        float fgv = fgB[(size_t)c * HWN + qglob];
        outB[(size_t)c * HWN + qglob] = fgv + mv * (att - fgv);
      }
    }
  }
}

extern "C" void kernel_launch(void* const* d_in, const int* in_sizes, int n_in,
                              void* d_out, int out_size, void* d_ws, size_t ws_size,
                              hipStream_t stream) {
  const float* background = (const float*)d_in[0];
  const float* foreground = (const float*)d_in[1];
  const float* mask       = (const float*)d_in[2];
  float* out = (float*)d_out;
  void* args[] = {(void*)&background, (void*)&foreground, (void*)&mask, (void*)&out};
  hipLaunchCooperativeKernel((void*)fused_kernel, dim3(256), dim3(512), args, 0, stream);
}

// Round 15
// 92.499 us; speedup vs baseline: 2.0011x; 2.0011x over previous
//
#include <hip/hip_runtime.h>
#include <math.h>

#define CC 64
#define HWN 4096
#define QB 64            // q per block; ALL 8 waves compute the same 64 q
#define KSPLIT 8         // each wave privately owns 512 k
#define KT 32
#define NITER (HWN / KSPLIT / KT)   // 16 chunks per wave
#define NKC (HWN / KT)              // 128 k-chunks per batch

typedef __attribute__((ext_vector_type(8))) short bf16x8;
typedef __attribute__((ext_vector_type(4))) float f32x4;

// precomputed bf16 operand layouts (written by prep_kernel every launch)
__device__ __align__(16) unsigned short g_bgT[4][HWN][CC];       // (bg*sb)^T [b][k][c]
__device__ __align__(16) unsigned short g_bgN[4][NKC][CC][KT];   // bf16(bg) chunk-major
__device__ __align__(16) unsigned short g_fgT[4][HWN][CC];       // (fg*sf)^T [b][q][c]

static __device__ __forceinline__ unsigned int f2bf(float x) {   // RNE
  union { float f; unsigned int u; } v; v.f = x;
  return (v.u + 0x7fffu + ((v.u >> 16) & 1u)) >> 16;
}
static __device__ __forceinline__ unsigned int packbf(float lo, float hi) {
  return f2bf(lo) | (f2bf(hi) << 16);
}

// ---- prep v2: 2x parallelism (16 waves/CU) ----
// grid 1024 = which(2) x b(4) x kc(128), 256 threads; each block = 32k x 64c
// tile (= exactly one bgN chunk). Norm: 8 threads/k x 8 c + shfl_xor{1,2,4}.
// All LDS patterns <=2-way bank aliasing (stride 65).
__global__ __launch_bounds__(256) void prep_kernel(const float* __restrict__ bg,
                                                   const float* __restrict__ fg) {
  __shared__ float lds[32 * 65];   // [k][c]
  const int bid = blockIdx.x;
  const int kc = bid & 127, b = (bid >> 7) & 3, which = bid >> 9;
  const float* src = (which ? fg : bg) + (size_t)b * CC * HWN + kc * KT;
  const int tid = threadIdx.x;

  // stage tile transposed: thread (c = tid>>2, kq = tid&3) loads 2 float4
  {
    int c = tid >> 2, k0 = (tid & 3) * 8;
#pragma unroll
    for (int j4 = 0; j4 < 2; ++j4) {
      float4 v = *(const float4*)(src + (size_t)c * HWN + k0 + 4 * j4);
      lds[(k0 + 4 * j4 + 0) * 65 + c] = v.x;
      lds[(k0 + 4 * j4 + 1) * 65 + c] = v.y;
      lds[(k0 + 4 * j4 + 2) * 65 + c] = v.z;
      lds[(k0 + 4 * j4 + 3) * 65 + c] = v.w;
    }
  }
  __syncthreads();

  const int k = tid >> 3, u = tid & 7;
  // column norm: 8 threads per k, each sums 8 c, combine via shfl (in-wave)
  float ss = 0.f;
#pragma unroll
  for (int j = 0; j < 8; ++j) {
    float v = lds[k * 65 + u * 8 + j];
    ss = fmaf(v, v, ss);
  }
  ss += __shfl_xor(ss, 1, 64);
  ss += __shfl_xor(ss, 2, 64);
  ss += __shfl_xor(ss, 4, 64);
  const float s = 1.0f / fmaxf(sqrtf(ss), 1e-12f);

  // write scaled transposed [b][k][c] bf16: 8 threads/k, one uint4 (8 c) each
  {
    unsigned int* gT32 = (unsigned int*)(which ? &g_fgT[0][0][0] : &g_bgT[0][0][0]);
    size_t R = (size_t)b * HWN + kc * KT + k;
    unsigned int w4[4];
#pragma unroll
    for (int i = 0; i < 4; ++i) {
      int c2 = u * 8 + 2 * i;
      w4[i] = packbf(lds[k * 65 + c2] * s, lds[k * 65 + c2 + 1] * s);
    }
    *(uint4*)&gT32[R * 32 + u * 4] = make_uint4(w4[0], w4[1], w4[2], w4[3]);
  }

  // bg blocks also write raw cast, chunk-major [b][kc][c][32]: thread
  // (cN = tid>>2, vN = tid&3) writes 8 k at k = vN*8 (one uint4)
  if (which == 0) {
    unsigned int* gN32 = (unsigned int*)&g_bgN[0][0][0][0];
    int cN = tid >> 2, vN = tid & 3;
    unsigned int n4[4];
#pragma unroll
    for (int i = 0; i < 4; ++i) {
      int kk = vN * 8 + 2 * i;
      n4[i] = packbf(lds[kk * 65 + cN], lds[(kk + 1) * 65 + cN]);
    }
    size_t RN = (((size_t)b * NKC + kc) * CC + cN) * (KT / 2) + vN * 4;
    *(uint4*)&gN32[RN] = make_uint4(n4[0], n4[1], n4[2], n4[3]);
  }
}

// ---- flash attention: r8/r13 exact (best measured: total 91.7us, attn ~35us) ----
// bgT via global_load_lds (4KB dbuf/wave), bgN chunk-major register dbuf,
// one vmcnt(8)/iter, zero loop barriers, XCD swizzle.
// LDS: [0,65536)        bgT staging, wave w: [w*8192 + buf*4096), swizzled
//      [65536,106496)   P per wave [64q][40k] ushort (5120 B each)
//      [106496,108544)  mL [8ks][64q] f32
//      epilogue aliases [0,69632) as mO [8ks][64c][34] f32 (two q-half passes)
#define P_OFF 65536
#define ML_OFF 106496
#define SMEM_BYTES 108544
__global__ __launch_bounds__(512, 2) void attn_kernel(const float* __restrict__ fg,
                                                      const float* __restrict__ mask,
                                                      float* __restrict__ out) {
  __shared__ __align__(16) char smem[SMEM_BYTES];
  // bijective XCD swizzle (256 % 8 == 0): 2 XCDs per batch -> 2MB working set/L2
  const int wg = blockIdx.x;
  const int wgp = (wg & 7) * 32 + (wg >> 3);
  const int b = wgp >> 6;
  const int q0 = (wgp & 63) * QB;
  const int tid = threadIdx.x;
  const int lane = tid & 63;
  const int ks = tid >> 6;    // 0..7, private K-split (512 k each)
  const int m16 = lane & 15;
  const int quad = lane >> 4;

  // fg B-fragments (64 q), loaded once from global (L2)
  bf16x8 Bf[4][2];
#pragma unroll
  for (int qf = 0; qf < 4; ++qf)
#pragma unroll
    for (int h = 0; h < 2; ++h)
      Bf[qf][h] = *(const bf16x8*)&g_fgT[b][q0 + qf * 16 + m16][h * 32 + quad * 8];

  // bgT lane-swizzled staging sources (swizzle on global side; LDS lane-ordered)
  const unsigned short* srcT[4];
#pragma unroll
  for (int t = 0; t < 4; ++t) {
    int uT = t * 64 + lane;
    int kk = uT >> 3, pos = uT & 7, j = pos ^ (kk & 7);
    srcT[t] = &g_bgT[b][ks * 512 + kk][j * 8];
  }

  // bgN per-lane base (chunk-major): chunk block ks*16, row c=m16, k-slice quad*8
  const unsigned short* pN = &g_bgN[b][ks * 16][m16][quad * 8];

  unsigned short* P = (unsigned short*)(smem + P_OFF + ks * 5120);  // [64 q][40 k]
  float* mL = (float*)(smem + ML_OFF);

  float l_run[4] = {0.f, 0.f, 0.f, 0.f};   // per-lane partial sums per q-frag
  f32x4 O[4][4];                            // [c-tile][q-frag]
#pragma unroll
  for (int t = 0; t < 4; ++t)
#pragma unroll
    for (int qf = 0; qf < 4; ++qf) O[t][qf] = (f32x4){0.f, 0.f, 0.f, 0.f};

  char* const myT = smem + ks * 8192;       // this wave's bgT staging (2 x 4KB)

  auto stageT = [&](int bufsel) {
#pragma unroll
    for (int t = 0; t < 4; ++t) {
      __builtin_amdgcn_global_load_lds(
          (const __attribute__((address_space(1))) unsigned int*)srcT[t],
          (__attribute__((address_space(3))) unsigned int*)(myT + bufsel * 4096 + t * 1024),
          16, 0, 0);
      srcT[t] += KT * CC;   // next chunk
    }
  };

  bf16x8 A0r[4], A1r[4];   // bgN register double-buffer (static-indexed)
  auto loadN = [&](bf16x8 (&A)[4], int ch) {
#pragma unroll
    for (int t = 0; t < 4; ++t)
      A[t] = *(const bf16x8*)(pN + (size_t)ch * (CC * KT) + t * 16 * KT);
  };

  // one pipeline step: compute chunk `it` from LDS buf `co` + regs Ac,
  // prefetching chunk it+1 into buf `co^1` + regs An.
  auto iter = [&](int it, int co, bf16x8 (&Ac)[4], bf16x8 (&An)[4]) {
    if (it + 1 < NITER) {
      stageT(co ^ 1);        // 4 x global_load_lds (bgT, chunk it+1)
      loadN(An, it + 1);     // 4 x global_load_dwordx4 (bgN, chunk it+1)
      // oldest-8 wait: chunk-it bgT glds AND chunk-it bgN reg loads complete
      asm volatile("s_waitcnt vmcnt(8)" ::: "memory");
    } else {
      asm volatile("s_waitcnt vmcnt(0)" ::: "memory");
    }

    const char* baseT = myT + co * 4096;

    // scores S[32k][64q] = (bg*sb)^T · (fg*sf): 4 ds_read feed 16 MFMA
    f32x4 S[4][2];
    __builtin_amdgcn_s_setprio(1);
#pragma unroll
    for (int i = 0; i < 2; ++i) {
      int kk = 16 * i + m16;
      bf16x8 T0 = *(const bf16x8*)(baseT + kk * 128 + ((quad) ^ (kk & 7)) * 16);
      bf16x8 T1 = *(const bf16x8*)(baseT + kk * 128 + ((4 + quad) ^ (kk & 7)) * 16);
#pragma unroll
      for (int qf = 0; qf < 4; ++qf) {
        f32x4 acc = {0.f, 0.f, 0.f, 0.f};
        acc = __builtin_amdgcn_mfma_f32_16x16x32_bf16(T0, Bf[qf][0], acc, 0, 0, 0);
        acc = __builtin_amdgcn_mfma_f32_16x16x32_bf16(T1, Bf[qf][1], acc, 0, 0, 0);
        S[qf][i] = acc;
      }
    }
    __builtin_amdgcn_s_setprio(0);

    // fixed-max softmax: cosines, |s| <= 1 -> p = exp(s-1); per-lane deferred sum
#pragma unroll
    for (int qf = 0; qf < 4; ++qf)
#pragma unroll
      for (int i = 0; i < 2; ++i) {
        float pe[4];
#pragma unroll
        for (int r = 0; r < 4; ++r) {
          pe[r] = __expf(S[qf][i][r] - 1.0f);
          l_run[qf] += pe[r];
        }
        // pack P -> per-wave LDS [q][k] bf16 (round-half-up via +0x8000, v_perm)
        union { float f; unsigned int u; } x0, x1, x2, x3;
        x0.f = pe[0]; x1.f = pe[1]; x2.f = pe[2]; x3.f = pe[3];
        unsigned int p01 = __builtin_amdgcn_perm(x1.u + 0x8000u, x0.u + 0x8000u, 0x07060302u);
        unsigned int p23 = __builtin_amdgcn_perm(x3.u + 0x8000u, x2.u + 0x8000u, 0x07060302u);
        *(uint2*)&P[(qf * 16 + m16) * 40 + 16 * i + quad * 4] = make_uint2(p01, p23);
      }

    // PV: O[c][q] += bg[c][k] · P[k][q]   (per-wave P + private regs: no barrier)
    bf16x8 Pf[4];
#pragma unroll
    for (int qf = 0; qf < 4; ++qf)
      Pf[qf] = *(const bf16x8*)&P[(qf * 16 + m16) * 40 + quad * 8];
    __builtin_amdgcn_s_setprio(1);
#pragma unroll
    for (int t = 0; t < 4; ++t)
#pragma unroll
      for (int qf = 0; qf < 4; ++qf)
        O[t][qf] = __builtin_amdgcn_mfma_f32_16x16x32_bf16(Ac[t], Pf[qf], O[t][qf], 0, 0, 0);
    __builtin_amdgcn_s_setprio(0);
  };

  // prologue: chunk 0 in flight (4 glds + 4 reg loads)
  stageT(0);
  loadN(A0r, 0);

  for (int it2 = 0; it2 < NITER; it2 += 2) {
    iter(it2,     0, A0r, A1r);
    iter(it2 + 1, 1, A1r, A0r);
  }

  // ---- merge 8 K-splits + epilogue (two q-half passes; mO aliases staging+P) ----
#pragma unroll
  for (int qf = 0; qf < 4; ++qf) {
    l_run[qf] += __shfl_xor(l_run[qf], 16, 64);
    l_run[qf] += __shfl_xor(l_run[qf], 32, 64);
  }
  if (quad == 0) {
#pragma unroll
    for (int qf = 0; qf < 4; ++qf) mL[ks * 64 + qf * 16 + m16] = l_run[qf];
  }
  float* mO = (float*)smem;   // [8 ks][64 c][34]
  const float* fgB = fg + (size_t)b * CC * HWN;
  const float* mk = mask + (size_t)b * HWN;
  float* outB = out + (size_t)b * CC * HWN;

#pragma unroll
  for (int half = 0; half < 2; ++half) {
    __syncthreads();   // pass 0: all waves done with staging/P reads; pass 1: reduce done
#pragma unroll
    for (int qh = 0; qh < 2; ++qh) {
      int qf = half * 2 + qh;
#pragma unroll
      for (int t = 0; t < 4; ++t)
#pragma unroll
        for (int r = 0; r < 4; ++r)
          mO[(ks * 64 + 16 * t + quad * 4 + r) * 34 + qh * 16 + m16] = O[t][qf][r];
    }
    __syncthreads();
    {
      int q = tid & 31, cb = tid >> 5;   // cb 0..15
      int qglob = q0 + half * 32 + q;
      float L = 0.f;
#pragma unroll
      for (int s = 0; s < 8; ++s) L += mL[s * 64 + half * 32 + q];
      float invL = 1.0f / L;
      float mv = mk[qglob];
#pragma unroll
      for (int e = 0; e < 4; ++e) {
        int c = cb * 4 + e;
        float acc = 0.f;
#pragma unroll
        for (int s = 0; s < 8; ++s) acc += mO[(s * 64 + c) * 34 + q];
        float att = acc * invL;
        float fgv = fgB[(size_t)c * HWN + qglob];
        outB[(size_t)c * HWN + qglob] = fgv + mv * (att - fgv);
      }
    }
  }
}

extern "C" void kernel_launch(void* const* d_in, const int* in_sizes, int n_in,
                              void* d_out, int out_size, void* d_ws, size_t ws_size,
                              hipStream_t stream) {
  const float* background = (const float*)d_in[0];
  const float* foreground = (const float*)d_in[1];
  const float* mask       = (const float*)d_in[2];
  float* out = (float*)d_out;
  prep_kernel<<<1024, 256, 0, stream>>>(background, foreground);
  attn_kernel<<<dim3(HWN / QB * 4), 512, 0, stream>>>(foreground, mask, out);
}